// Round 2
// baseline (28.769 us; speedup 1.0000x reference)
//
#include <hip/hip_runtime.h>

// REM generator: out[h][i][j], 8 x 2048 x 2048 f32.
// Every element is a function of d = i - j only:
//   V[d] = (d % n == 0) ? F[Lc(d)] * G[Lc(d/n)] : 0,   Lc(x) = (x <= 200) ? x : 0
// with the -eye baked into V[0]. Hot loop: one reversed-float4 LDS read + store.

#define CAP  200
#define ROWS 16
#define T    2048

__device__ __forceinline__ float ipow_f(float base, int L) {
    // sign-correct integer power (matches _ipow)
    float mag = powf(fabsf(base), (float)L);
    float sgn = ((L & 1) && (base < 0.0f)) ? -1.0f : 1.0f;
    return sgn * mag;
}

__global__ __launch_bounds__(256) void rem_kernel(
    const float* __restrict__ eta,
    const float* __restrict__ nu,
    const float* __restrict__ theta,
    float* __restrict__ out)
{
    __shared__ float  V[T];            // 8 KB: value per diagonal offset
    __shared__ float4 R[4 * 512];      // 32 KB: phase-split reversed windows

    const int h    = blockIdx.y;
    const int row0 = blockIdx.x * ROWS;
    const int tid  = threadIdx.x;

    // ---- stage 1: V[k], k = 0..2047 (8 entries/thread) ----
    for (int k = tid; k < T; k += 256) {
        const int Lk = (k <= CAP) ? k : 0;
        float val;
        switch (h) {
        case 0: case 1:
            val = ipow_f(tanhf(eta[h]), Lk);
            break;
        case 2: {                                  // dilate(lam2^L, 4)
            if (k & 3) { val = 0.0f; }
            else { int q = k >> 2; int Lq = (q <= CAP) ? q : 0;
                   val = ipow_f(tanhf(eta[2]), Lq); }
        } break;
        case 3: case 4: {                          // gam^L * cos(theta*L)
            float gm = 1.0f / (1.0f + expf(-nu[h - 3]));
            val = ipow_f(gm, Lk) * cosf(theta[h - 3] * (float)Lk);
        } break;
        case 5: {                                  // gam2^L * sin(theta2*L)
            float gm = 1.0f / (1.0f + expf(-nu[2]));
            val = ipow_f(gm, Lk) * sinf(theta[2] * (float)Lk);
        } break;
        case 6: {                                  // dilate(cos(t3*L),3) * cos(t3*L)
            int q = k / 3;
            if (k - q * 3) { val = 0.0f; }
            else { int Lq = (q <= CAP) ? q : 0;
                   val = cosf(theta[3] * (float)Lk) * cosf(theta[3] * (float)Lq); }
        } break;
        default: {                                 // dilate(sin(t4*L),2) * sin(t4*L)
            if (k & 1) { val = 0.0f; }
            else { int q = k >> 1; int Lq = (q <= CAP) ? q : 0;
                   val = sinf(theta[4] * (float)Lk) * sinf(theta[4] * (float)Lq); }
        } break;
        }
        if (k == 0) val -= 1.0f;                   // bake -eye into V[0]
        V[k] = val;
    }
    __syncthreads();

    // ---- stage 2: R[p][m] = {V[4m+p], V[4m+p-1], V[4m+p-2], V[4m+p-3]} ----
    const float4* V4 = reinterpret_cast<const float4*>(V);
    #pragma unroll
    for (int it = 0; it < 8; ++it) {
        const int p = it >> 1;                     // compile-time phase
        const int m = ((it & 1) << 8) + tid;       // 0..511
        float4 A = V4[m];
        float4 B = V4[(m > 0) ? (m - 1) : 0];
        if (m == 0) B = make_float4(0.f, 0.f, 0.f, 0.f);
        float4 w;
        if      (p == 0) w = make_float4(A.x, B.w, B.z, B.y);
        else if (p == 1) w = make_float4(A.y, A.x, B.w, B.z);
        else if (p == 2) w = make_float4(A.z, A.y, A.x, B.w);
        else             w = make_float4(A.w, A.z, A.y, A.x);
        R[p * 512 + m] = w;
    }
    __syncthreads();

    // ---- stage 3: stream stores. one b128 LDS read + one dwordx4 store per f4 ----
    float4* out4 = reinterpret_cast<float4*>(out) + (size_t)h * (T * 512);
    #pragma unroll 8
    for (int k2 = 0; k2 < ROWS * 2; ++k2) {
        const int r  = k2 >> 1;
        const int c4 = ((k2 & 1) << 8) + tid;
        const int i  = row0 + r;
        const int p  = i & 3;                      // wave-uniform
        const int m  = (i >> 2) - c4;              // lane stride -1 -> conflict-free
        float4 t = R[p * 512 + ((m > 0) ? m : 0)];
        float4 v = (m >= 0) ? t : make_float4(0.f, 0.f, 0.f, 0.f);
        out4[(size_t)i * 512 + c4] = v;
    }
}

extern "C" void kernel_launch(void* const* d_in, const int* in_sizes, int n_in,
                              void* d_out, int out_size, void* d_ws, size_t ws_size,
                              hipStream_t stream) {
    (void)in_sizes; (void)n_in; (void)d_ws; (void)ws_size; (void)out_size;
    const float* eta   = (const float*)d_in[0];
    const float* nu    = (const float*)d_in[1];
    const float* theta = (const float*)d_in[2];
    float* out = (float*)d_out;

    dim3 grid(T / ROWS, 8, 1);   // 128 x 8 = 1024 blocks, 4/CU (LDS-limited)
    rem_kernel<<<grid, 256, 0, stream>>>(eta, nu, theta, out);
}